// Round 14
// baseline (77.309 us; speedup 1.0000x reference)
//
#include <hip/hip_runtime.h>
#include <hip/hip_bf16.h>

// y[b,i,j] = s[b,i] + s[b,j] - 2 * sum_k U[b,i,k]*U[b,j,k],  U = bf16(g^t * V)
//   (w*Vi*Vj = (g^t Vi)(g^t Vj), w = max(G,0)^(2t))  s[b,i] = sum_k U[b,i,k]^2
// bs=4, r=4096, d=64. Output 268 MB fp32 -> write-bandwidth bound.
// R13 -> R14: full-width row tiles to test DRAM page locality UNCONFOUNDED.
// Block = 32 rows x 4096 (all j), j-loop in 512-col steps. Each wave owns
// 4 rows for the whole block -> its store stream advances GAPLESSLY across
// each 16KB row (was: 1KB runs + 16KB hops). A (4KB) in regs once; B panel
// swept per step, L2-shared across co-resident blocks (U=2MB, NT writes
// don't evict it). LDS 32x516 f32 = 64.5KB -> 2 blocks/CU. Same dwordx4
// NT stores + lgkm-only barriers as R9.

typedef __attribute__((ext_vector_type(8))) short bf16x8;   // 8 bf16 = 4 VGPRs
typedef __attribute__((ext_vector_type(4))) float f32x4;

constexpr int BS = 4, R = 4096, D = 64;
constexpr int JS = 512;          // j-step width
constexpr int LS = JS + 4;       // LDS row stride (floats), 16B-aligned pad

__device__ __forceinline__ void barrier_lds_only() {
    // order LDS ops, but let global (NT) stores stay in flight
    asm volatile("s_waitcnt lgkmcnt(0)" ::: "memory");
    __builtin_amdgcn_sched_barrier(0);
    __builtin_amdgcn_s_barrier();
    __builtin_amdgcn_sched_barrier(0);
}

// ---------------------------------------------------------------- prep ------
// One wave per row (64 lanes == d). Emits U = bf16(g^t * V), fp32 s = sum U^2.
__global__ __launch_bounds__(256) void prep_kernel(
    const float* __restrict__ G, const float* __restrict__ V,
    const float* __restrict__ wt,
    __hip_bfloat16* __restrict__ u_bf, float* __restrict__ s)
{
    int row  = blockIdx.x * 4 + (threadIdx.x >> 6);   // global row in [0, BS*R)
    int lane = threadIdx.x & 63;                       // k index (d == 64)
    if (row >= BS * R) return;
    int b = row / R;

    float t  = wt[0];
    float g  = fmaxf(G[b * D + lane], 0.0f);
    float sw = powf(g, t);                             // g^t; 0^0==1 matches jnp
    float u  = sw * V[(size_t)row * D + lane];

    __hip_bfloat16 ub = __float2bfloat16(u);
    u_bf[(size_t)row * D + lane] = ub;

    // s from the same bf16-rounded values -> diagonal cancels vs MFMA cross
    float uf   = __bfloat162float(ub);
    float prod = uf * uf;
    #pragma unroll
    for (int off = 32; off; off >>= 1) prod += __shfl_down(prod, off);
    if (lane == 0) s[row] = prod;
}

// ---------------------------------------------------------------- dist ------
// Block: 512 threads = 8 waves. Tile: 32 rows x FULL 4096 j, swept in 8
// steps of 512 j-cols; per step each wave does a 32x64 sub-tile.
// Grid: 512 one-dim blocks (b = bid>>7, i0 = (bid&127)*32) — whole grid
// co-resident (2 blocks/CU).
// MFMA 16x16x32 bf16 layouts (HW-verified, learn_hip m89/m91/m97):
//   A: lane holds A[row=l&15][k=(l>>4)*8 + 0..7]   (contiguous 16B)
//   B: lane holds B[k=(l>>4)*8 + 0..7][col=l&15] == U[j+(l&15)][k...] for B=U^T
//   C/D: col = l&15, row = (l>>4)*4 + reg
// Epilogue per step: y -> LDS[32][516] -> wave w stores its 4 fixed rows
// (w*4..w*4+3), 2x 1KB dwordx4 per row; streams advance gaplessly in j.
__global__ __launch_bounds__(512) void dist_kernel(
    const short* __restrict__ U, const float* __restrict__ s,
    float* __restrict__ out)
{
    __shared__ float lds[32 * LS];   // 64.5 KB -> 2 blocks/CU

    int lane = threadIdx.x & 63;
    int wave = threadIdx.x >> 6;     // 0..7 (j position within step)
    int lrow = lane & 15;
    int kgrp = lane >> 4;            // 0..3

    int bid = blockIdx.x;
    int b   = bid >> 7;
    int i0  = (bid & 127) * 32;

    const short* Ap = U + ((size_t)b * R + i0) * D;   // 32 rows x 64
    const short* Bb = U + (size_t)b * R * D;          // full batch panel
    const float* sb = s + (size_t)b * R;

    // A fragments: 2 row-blocks x 2 K-steps — loaded ONCE
    bf16x8 a[2][2];
    #pragma unroll
    for (int rb = 0; rb < 2; ++rb)
        #pragma unroll
        for (int ks = 0; ks < 2; ++ks)
            a[rb][ks] = *(const bf16x8*)(Ap + (rb * 16 + lrow) * D + ks * 32 + kgrp * 8);

    float si_lane = sb[i0 + (lane & 31)];   // lane c (c<32) holds s[i0+c]
    float* outb = out + ((size_t)b * R + i0) * R;

    for (int jx = 0; jx < R / JS; ++jx) {
        int jw = jx * JS + wave * 64;       // this wave's 64-col window

        f32x4 acc[2][4];
        #pragma unroll
        for (int rb = 0; rb < 2; ++rb)
            #pragma unroll
            for (int jt = 0; jt < 4; ++jt)
                acc[rb][jt] = f32x4{0.f, 0.f, 0.f, 0.f};

        const short* Bp = Bb + (size_t)jw * D;
        #pragma unroll
        for (int jt = 0; jt < 4; ++jt) {
            const short* Bt = Bp + jt * 16 * D;
            bf16x8 b0 = *(const bf16x8*)(Bt + lrow * D +      kgrp * 8);
            bf16x8 b1 = *(const bf16x8*)(Bt + lrow * D + 32 + kgrp * 8);
            #pragma unroll
            for (int rb = 0; rb < 2; ++rb) {
                acc[rb][jt] = __builtin_amdgcn_mfma_f32_16x16x32_bf16(a[rb][0], b0, acc[rb][jt], 0, 0, 0);
                acc[rb][jt] = __builtin_amdgcn_mfma_f32_16x16x32_bf16(a[rb][1], b1, acc[rb][jt], 0, 0, 0);
            }
        }

        // epilogue part 1: y -> LDS step tile [32][512]
        #pragma unroll
        for (int rb = 0; rb < 2; ++rb) {
            #pragma unroll
            for (int rg = 0; rg < 4; ++rg) {
                int rl = rb * 16 + kgrp * 4 + rg;           // 0..31 local row
                float si = __shfl(si_lane, rl);
                #pragma unroll
                for (int jt = 0; jt < 4; ++jt) {
                    float sj = sb[jw + jt * 16 + lrow];
                    float y  = si + sj - 2.0f * acc[rb][jt][rg];
                    lds[rl * LS + wave * 64 + jt * 16 + lrow] = y;
                }
            }
        }
        barrier_lds_only();   // ds_writes visible; global stores NOT drained

        // epilogue part 2: wave w stores its 4 FIXED rows, 2x 1KB each.
        // Across jx these advance contiguously along each 16KB output row.
        #pragma unroll
        for (int r = 0; r < 4; ++r) {
            int rl = wave * 4 + r;
            #pragma unroll
            for (int t = 0; t < 2; ++t) {
                f32x4 v = *(const f32x4*)&lds[rl * LS + t * 256 + lane * 4];
                __builtin_nontemporal_store(v,
                    (f32x4*)(outb + (size_t)rl * R + jx * JS + t * 256 + lane * 4));
            }
        }
        barrier_lds_only();   // ds_reads done -> next step may overwrite LDS
    }
}

// --------------------------------------------------------------------------
extern "C" void kernel_launch(void* const* d_in, const int* in_sizes, int n_in,
                              void* d_out, int out_size, void* d_ws, size_t ws_size,
                              hipStream_t stream) {
    const float* G  = (const float*)d_in[0];
    const float* V  = (const float*)d_in[1];
    const float* wt = (const float*)d_in[2];
    float* out = (float*)d_out;

    char* ws = (char*)d_ws;
    __hip_bfloat16* u_bf = (__hip_bfloat16*)ws;                             // 2 MB
    float*          s    = (float*)        (ws + (size_t)BS * R * D * 2);   // 64 KB

    prep_kernel<<<BS * R / 4, 256, 0, stream>>>(G, V, wt, u_bf, s);

    dist_kernel<<<BS * (R / 32), 512, 0, stream>>>((const short*)u_bf, s, out);
}

// Round 15
// 64.456 us; speedup vs baseline: 1.1994x; 1.1994x over previous
//
#include <hip/hip_runtime.h>
#include <hip/hip_bf16.h>

// y[b,i,j] = s[b,i] + s[b,j] - 2 * sum_k U[b,i,k]*U[b,j,k],  U = bf16(g^t * V)
//   (w*Vi*Vj = (g^t Vi)(g^t Vj), w = max(G,0)^(2t))  s[b,i] = sum_k U[b,i,k]^2
// bs=4, r=4096, d=64. Output 268 MB fp32 -> write-bandwidth bound.
// R14 -> R15: revert to R9 (best, 64.7). SINGLE CHANGE vs R9: PLAIN stores
// instead of NT. With lgkm-only barriers (no vmcnt drain anywhere), plain
// write-back stores let the 4MB/XCD L2 act as a coalescing buffer that
// decouples HBM write progress from bursty wave issue; NT bypassed it.
// (R4's plain-vs-NT "neutral" was measured WITH forced vmcnt(0) drains.)

typedef __attribute__((ext_vector_type(8))) short bf16x8;   // 8 bf16 = 4 VGPRs
typedef __attribute__((ext_vector_type(4))) float f32x4;

constexpr int BS = 4, R = 4096, D = 64;
constexpr int LS = 260;   // LDS row stride (floats): 16B-aligned rows, 2-way max conflict (free)

__device__ __forceinline__ void barrier_lds_only() {
    // order LDS ops, but let global stores stay in flight
    asm volatile("s_waitcnt lgkmcnt(0)" ::: "memory");
    __builtin_amdgcn_sched_barrier(0);
    __builtin_amdgcn_s_barrier();
    __builtin_amdgcn_sched_barrier(0);
}

// ---------------------------------------------------------------- prep ------
// One wave per row (64 lanes == d). Emits U = bf16(g^t * V), fp32 s = sum U^2.
__global__ __launch_bounds__(256) void prep_kernel(
    const float* __restrict__ G, const float* __restrict__ V,
    const float* __restrict__ wt,
    __hip_bfloat16* __restrict__ u_bf, float* __restrict__ s)
{
    int row  = blockIdx.x * 4 + (threadIdx.x >> 6);   // global row in [0, BS*R)
    int lane = threadIdx.x & 63;                       // k index (d == 64)
    if (row >= BS * R) return;
    int b = row / R;

    float t  = wt[0];
    float g  = fmaxf(G[b * D + lane], 0.0f);
    float sw = powf(g, t);                             // g^t; 0^0==1 matches jnp
    float u  = sw * V[(size_t)row * D + lane];

    __hip_bfloat16 ub = __float2bfloat16(u);
    u_bf[(size_t)row * D + lane] = ub;

    // s from the same bf16-rounded values -> diagonal cancels vs MFMA cross
    float uf   = __bfloat162float(ub);
    float prod = uf * uf;
    #pragma unroll
    for (int off = 32; off; off >>= 1) prod += __shfl_down(prod, off);
    if (lane == 0) s[row] = prod;
}

// ---------------------------------------------------------------- dist ------
// Block: 512 threads = 8 waves, arranged 2 (i) x 4 (j); wave tile 64x64.
// Block tile 128 (i) x 256 (j). Grid: (R/256 j [FAST], R/128 i, BS).
// MFMA 16x16x32 bf16 layouts (HW-verified, learn_hip m89/m91/m97):
//   A: lane holds A[row=l&15][k=(l>>4)*8 + 0..7]   (contiguous 16B)
//   B: lane holds B[k=(l>>4)*8 + 0..7][col=l&15] == U[j0+(l&15)][k...] for B=U^T
//   C/D: col = l&15, row = (l>>4)*4 + reg
// Epilogue: two 64-row chunks: y -> LDS[64][260] -> full-row 1KB stores.
__global__ __launch_bounds__(512) void dist_kernel(
    const short* __restrict__ U, const float* __restrict__ s,
    float* __restrict__ out)
{
    __shared__ float lds[64 * LS];   // 66.5 KB -> 2 blocks/CU

    int lane = threadIdx.x & 63;
    int wave = threadIdx.x >> 6;     // 0..7
    int wr   = wave >> 2;            // 0..1  (i half)
    int wc   = wave & 3;             // 0..3  (j quarter)

    int b  = blockIdx.z;
    int jb = blockIdx.x * 256;       // FAST axis: j -> contiguous write window
    int i0 = blockIdx.y * 128;

    const short* Ap = U + ((size_t)b * R + i0 + wr * 64) * D;   // 64 rows
    const short* Bp = U + ((size_t)b * R + jb + wc * 64) * D;   // 64 rows
    const float* sb = s + (size_t)b * R;

    int lrow = lane & 15;
    int kgrp = lane >> 4;            // 0..3

    // A fragments: 4 row-blocks x 2 K-steps
    bf16x8 a[4][2];
    #pragma unroll
    for (int rb = 0; rb < 4; ++rb)
        #pragma unroll
        for (int ks = 0; ks < 2; ++ks)
            a[rb][ks] = *(const bf16x8*)(Ap + (rb * 16 + lrow) * D + ks * 32 + kgrp * 8);

    f32x4 acc[4][4];
    #pragma unroll
    for (int rb = 0; rb < 4; ++rb)
        #pragma unroll
        for (int jt = 0; jt < 4; ++jt)
            acc[rb][jt] = f32x4{0.f, 0.f, 0.f, 0.f};

    #pragma unroll
    for (int jt = 0; jt < 4; ++jt) {
        const short* Bt = Bp + jt * 16 * D;
        bf16x8 b0 = *(const bf16x8*)(Bt + lrow * D +      kgrp * 8);
        bf16x8 b1 = *(const bf16x8*)(Bt + lrow * D + 32 + kgrp * 8);
        #pragma unroll
        for (int rb = 0; rb < 4; ++rb) {
            acc[rb][jt] = __builtin_amdgcn_mfma_f32_16x16x32_bf16(a[rb][0], b0, acc[rb][jt], 0, 0, 0);
            acc[rb][jt] = __builtin_amdgcn_mfma_f32_16x16x32_bf16(a[rb][1], b1, acc[rb][jt], 0, 0, 0);
        }
    }

    // per-lane row sums for this wave's 64 rows
    float si_lane = sb[i0 + wr * 64 + lane];

    float* outb = out + ((size_t)b * R + i0) * R + jb;

    #pragma unroll
    for (int c = 0; c < 2; ++c) {
        // chunk c covers block rows c*64 .. c*64+63 (i.e. waves with wr==c)
        if (wr == c) {
            #pragma unroll
            for (int rb = 0; rb < 4; ++rb) {
                #pragma unroll
                for (int rg = 0; rg < 4; ++rg) {
                    int rl = rb * 16 + kgrp * 4 + rg;          // 0..63 local row
                    float si = __shfl(si_lane, rl);
                    #pragma unroll
                    for (int jt = 0; jt < 4; ++jt) {
                        float sj = sb[jb + wc * 64 + jt * 16 + lrow];
                        float y  = si + sj - 2.0f * acc[rb][jt][rg];
                        lds[rl * LS + wc * 64 + jt * 16 + lrow] = y;
                    }
                }
            }
        }
        barrier_lds_only();   // ds_writes visible; in-flight global stores NOT drained

        // all 8 waves store chunk c: wave w -> rows w*8..w*8+7 of the chunk.
        // Each instruction: 64 lanes x 16B = one contiguous 1KB segment.
        #pragma unroll
        for (int r = 0; r < 8; ++r) {
            int rl = wave * 8 + r;
            f32x4 v = *(const f32x4*)&lds[rl * LS + lane * 4];
            *(f32x4*)(outb + (size_t)(c * 64 + rl) * R + lane * 4) = v;
        }
        if (c == 0) barrier_lds_only();   // ds_reads done -> chunk-1 may overwrite LDS
    }
}

// --------------------------------------------------------------------------
extern "C" void kernel_launch(void* const* d_in, const int* in_sizes, int n_in,
                              void* d_out, int out_size, void* d_ws, size_t ws_size,
                              hipStream_t stream) {
    const float* G  = (const float*)d_in[0];
    const float* V  = (const float*)d_in[1];
    const float* wt = (const float*)d_in[2];
    float* out = (float*)d_out;

    char* ws = (char*)d_ws;
    __hip_bfloat16* u_bf = (__hip_bfloat16*)ws;                             // 2 MB
    float*          s    = (float*)        (ws + (size_t)BS * R * D * 2);   // 64 KB

    prep_kernel<<<BS * R / 4, 256, 0, stream>>>(G, V, wt, u_bf, s);

    dim3 grid(R / 256, R / 128, BS);   // j fastest -> contiguous write window
    dist_kernel<<<grid, 512, 0, stream>>>((const short*)u_bf, s, out);
}